// Round 8
// baseline (215.588 us; speedup 1.0000x reference)
//
#include <hip/hip_runtime.h>

#define N_NODES 100000
#define N_EDGES 1600000
#define IN_F 256
#define OUT_F 128

#define CAP 48                               // slots per row (max degree ~36 expected)
#define GEMM_BLOCKS ((N_NODES + 127) / 128)  // 782
#define SCAT_BLOCKS 1024

typedef unsigned long long ull;
typedef __attribute__((ext_vector_type(4))) float f32x4;
typedef __attribute__((ext_vector_type(8))) short bf16x8;

__device__ __forceinline__ unsigned short f2bf(float f) {
    unsigned u = __float_as_uint(f);
    unsigned r = u + 0x7FFF + ((u >> 16) & 1);    // round-to-nearest-even
    return (unsigned short)(r >> 16);
}
__device__ __forceinline__ float bflo(unsigned u) { return __uint_as_float(u << 16); }
__device__ __forceinline__ float bfhi(unsigned u) { return __uint_as_float(u & 0xFFFF0000u); }

// ---------------------------------------------------------------------------
// W convert: Wt[n][k] = bf16(W[k][n])
// ---------------------------------------------------------------------------
__global__ __launch_bounds__(256) void wconv_kernel(const float* __restrict__ W,
                                                    unsigned short* __restrict__ Wt) {
    int idx = blockIdx.x * 256 + threadIdx.x;      // 32768 total
    int n = idx >> 8;
    int k = idx & 255;
    Wt[n * IN_F + k] = f2bf(W[k * OUT_F + n]);
}

// ---------------------------------------------------------------------------
// FUSED: blocks [0, GEMM_BLOCKS) -> MFMA GEMM (compute-bound)
//        blocks [GEMM_BLOCKS, +SCAT_BLOCKS) -> edge scatter (memory-bound)
// Co-resident on CUs: scatter rides under gemm's HBM headroom.
// ---------------------------------------------------------------------------
__global__ __launch_bounds__(256) void fused_kernel(const float* __restrict__ X,
                                                    const unsigned short* __restrict__ Wt,
                                                    unsigned short* __restrict__ support_bf,
                                                    const int* __restrict__ erow,
                                                    const int* __restrict__ ecol,
                                                    const float* __restrict__ eval,
                                                    int* __restrict__ rowcnt,
                                                    ull* __restrict__ slots) {
    __shared__ __align__(16) unsigned short Albs[4][128][8];   // 8 KB
    __shared__ __align__(16) unsigned short Blbs[4][128][8];   // 8 KB

    if (blockIdx.x >= GEMM_BLOCKS) {
        // ---------------- edge scatter ----------------
        const int start = (blockIdx.x - GEMM_BLOCKS) * 256 + threadIdx.x;
        for (int e = start; e < N_EDGES; e += SCAT_BLOCKS * 256) {
            int row = erow[e];
            int pos = atomicAdd(&rowcnt[row], 1);
            if (pos < CAP) {
                ull rec = ((ull)__float_as_uint(eval[e]) << 32) | (unsigned)ecol[e];
                slots[(long)row * CAP + pos] = rec;
            }
        }
        return;
    }

    // ---------------- MFMA GEMM ----------------
    const int tid = threadIdx.x;
    const int block_row = blockIdx.x * 128;

    const int srow = tid >> 1;          // 0..127
    const int shalf = tid & 1;

    const int wid = tid >> 6;
    const int lane = tid & 63;
    const int wr = wid >> 1, wc = wid & 1;
    const int fr = lane & 15;
    const int kb = lane >> 4;

    const int agrow = block_row + srow;
    const bool arow_ok = (agrow < N_NODES);
    const float* xrow = X + (long)agrow * IN_F;
    const unsigned short* wrow = Wt + srow * IN_F;

    f32x4 acc[4][4];
#pragma unroll
    for (int m = 0; m < 4; ++m)
#pragma unroll
        for (int n = 0; n < 4; ++n) acc[m][n] = (f32x4)0.f;

    // prologue loads (k0 = 0)
    float4 c0, c1, c2, c3;
    bf16x8 cb0, cb1;
    if (arow_ok) {
        c0 = *(const float4*)&xrow[shalf * 16 + 0];
        c1 = *(const float4*)&xrow[shalf * 16 + 4];
        c2 = *(const float4*)&xrow[shalf * 16 + 8];
        c3 = *(const float4*)&xrow[shalf * 16 + 12];
    } else {
        c0 = c1 = c2 = c3 = make_float4(0.f, 0.f, 0.f, 0.f);
    }
    cb0 = *(const bf16x8*)&wrow[shalf * 16];
    cb1 = *(const bf16x8*)&wrow[shalf * 16 + 8];

#pragma unroll
    for (int k0 = 0; k0 < IN_F; k0 += 32) {
        // stage current into LDS
        {
            bf16x8 p0, p1;
            p0[0] = (short)f2bf(c0.x); p0[1] = (short)f2bf(c0.y);
            p0[2] = (short)f2bf(c0.z); p0[3] = (short)f2bf(c0.w);
            p0[4] = (short)f2bf(c1.x); p0[5] = (short)f2bf(c1.y);
            p0[6] = (short)f2bf(c1.z); p0[7] = (short)f2bf(c1.w);
            p1[0] = (short)f2bf(c2.x); p1[1] = (short)f2bf(c2.y);
            p1[2] = (short)f2bf(c2.z); p1[3] = (short)f2bf(c2.w);
            p1[4] = (short)f2bf(c3.x); p1[5] = (short)f2bf(c3.y);
            p1[6] = (short)f2bf(c3.z); p1[7] = (short)f2bf(c3.w);
            *(bf16x8*)&Albs[shalf * 2][srow][0]     = p0;
            *(bf16x8*)&Albs[shalf * 2 + 1][srow][0] = p1;
            *(bf16x8*)&Blbs[shalf * 2][srow][0]     = cb0;
            *(bf16x8*)&Blbs[shalf * 2 + 1][srow][0] = cb1;
        }
        // prefetch next k-step (overlaps barrier + MFMA)
        float4 n0, n1, n2, n3;
        bf16x8 nb0, nb1;
        if (k0 + 32 < IN_F) {
            int kn = k0 + 32;
            if (arow_ok) {
                n0 = *(const float4*)&xrow[kn + shalf * 16 + 0];
                n1 = *(const float4*)&xrow[kn + shalf * 16 + 4];
                n2 = *(const float4*)&xrow[kn + shalf * 16 + 8];
                n3 = *(const float4*)&xrow[kn + shalf * 16 + 12];
            } else {
                n0 = n1 = n2 = n3 = make_float4(0.f, 0.f, 0.f, 0.f);
            }
            nb0 = *(const bf16x8*)&wrow[kn + shalf * 16];
            nb1 = *(const bf16x8*)&wrow[kn + shalf * 16 + 8];
        }
        __syncthreads();

        bf16x8 af[4], bfr[4];
#pragma unroll
        for (int m = 0; m < 4; ++m)
            af[m] = *(const bf16x8*)&Albs[kb][wr * 64 + m * 16 + fr][0];
#pragma unroll
        for (int n = 0; n < 4; ++n)
            bfr[n] = *(const bf16x8*)&Blbs[kb][wc * 64 + n * 16 + fr][0];
#pragma unroll
        for (int m = 0; m < 4; ++m)
#pragma unroll
            for (int n = 0; n < 4; ++n)
                acc[m][n] = __builtin_amdgcn_mfma_f32_16x16x32_bf16(af[m], bfr[n],
                                                                    acc[m][n], 0, 0, 0);
        __syncthreads();

        c0 = n0; c1 = n1; c2 = n2; c3 = n3;
        cb0 = nb0; cb1 = nb1;
    }

    // epilogue: C/D layout col=lane&15, row=(lane>>4)*4+reg ; write bf16
    const int crow0 = (lane >> 4) * 4;
    const int ccol = lane & 15;
#pragma unroll
    for (int m = 0; m < 4; ++m) {
#pragma unroll
        for (int reg = 0; reg < 4; ++reg) {
            int grow = block_row + wr * 64 + m * 16 + crow0 + reg;
            if (grow < N_NODES) {
#pragma unroll
                for (int n = 0; n < 4; ++n) {
                    int gcol = wc * 64 + n * 16 + ccol;
                    support_bf[(long)grow * OUT_F + gcol] = f2bf(acc[m][n][reg]);
                }
            }
        }
    }
}

// ---------------------------------------------------------------------------
// SpMM: FOUR rows per wave, 2-deep fused main loop -> 8 gathers in flight.
// Reads per-row slot regions (contiguous); NT stores on out.
// ---------------------------------------------------------------------------
__global__ __launch_bounds__(256) void spmm_kernel(const int* __restrict__ rowcnt,
                                                   const ull* __restrict__ slots,
                                                   const unsigned short* __restrict__ sbf,
                                                   const float* __restrict__ b,
                                                   float* __restrict__ out) {
    const int wave = blockIdx.x * 4 + (threadIdx.x >> 6);
    const int lane = threadIdx.x & 63;
    const int r0 = wave * 4;
    if (r0 >= N_NODES) return;                  // 100000 % 16 == 0 -> always full
    const int lo = lane * 2;
    const float2 bb = *(const float2*)&b[lo];

    int4 c4 = *(const int4*)&rowcnt[r0];
    const int cA = min(c4.x, CAP), cB = min(c4.y, CAP);
    const int cC = min(c4.z, CAP), cD = min(c4.w, CAP);
    const ull* pA = slots + (long)r0 * CAP;
    const ull* pB = pA + CAP;
    const ull* pC = pB + CAP;
    const ull* pD = pC + CAP;

    float2 aA = bb, aB = bb, aC = bb, aD = bb;

    const int mn = min(min(cA, cB), min(cC, cD));
    int i = 0;
    // fused main loop: 2 edges from each of 4 rows -> 8 independent gathers
    for (; i + 2 <= mn; i += 2) {
        ull rA0 = pA[i], rA1 = pA[i + 1];
        ull rB0 = pB[i], rB1 = pB[i + 1];
        ull rC0 = pC[i], rC1 = pC[i + 1];
        ull rD0 = pD[i], rD1 = pD[i + 1];
        unsigned uA0 = *(const unsigned*)&sbf[(long)(unsigned)rA0 * OUT_F + lo];
        unsigned uA1 = *(const unsigned*)&sbf[(long)(unsigned)rA1 * OUT_F + lo];
        unsigned uB0 = *(const unsigned*)&sbf[(long)(unsigned)rB0 * OUT_F + lo];
        unsigned uB1 = *(const unsigned*)&sbf[(long)(unsigned)rB1 * OUT_F + lo];
        unsigned uC0 = *(const unsigned*)&sbf[(long)(unsigned)rC0 * OUT_F + lo];
        unsigned uC1 = *(const unsigned*)&sbf[(long)(unsigned)rC1 * OUT_F + lo];
        unsigned uD0 = *(const unsigned*)&sbf[(long)(unsigned)rD0 * OUT_F + lo];
        unsigned uD1 = *(const unsigned*)&sbf[(long)(unsigned)rD1 * OUT_F + lo];
        float vA0 = __uint_as_float((unsigned)(rA0 >> 32));
        float vA1 = __uint_as_float((unsigned)(rA1 >> 32));
        float vB0 = __uint_as_float((unsigned)(rB0 >> 32));
        float vB1 = __uint_as_float((unsigned)(rB1 >> 32));
        float vC0 = __uint_as_float((unsigned)(rC0 >> 32));
        float vC1 = __uint_as_float((unsigned)(rC1 >> 32));
        float vD0 = __uint_as_float((unsigned)(rD0 >> 32));
        float vD1 = __uint_as_float((unsigned)(rD1 >> 32));
        aA.x += vA0 * bflo(uA0) + vA1 * bflo(uA1);
        aA.y += vA0 * bfhi(uA0) + vA1 * bfhi(uA1);
        aB.x += vB0 * bflo(uB0) + vB1 * bflo(uB1);
        aB.y += vB0 * bfhi(uB0) + vB1 * bfhi(uB1);
        aC.x += vC0 * bflo(uC0) + vC1 * bflo(uC1);
        aC.y += vC0 * bfhi(uC0) + vC1 * bfhi(uC1);
        aD.x += vD0 * bflo(uD0) + vD1 * bflo(uD1);
        aD.y += vD0 * bfhi(uD0) + vD1 * bfhi(uD1);
    }
    if (i < mn) {                              // one more from each row
        ull rA = pA[i], rB = pB[i], rC = pC[i], rD = pD[i];
        unsigned uA = *(const unsigned*)&sbf[(long)(unsigned)rA * OUT_F + lo];
        unsigned uB = *(const unsigned*)&sbf[(long)(unsigned)rB * OUT_F + lo];
        unsigned uC = *(const unsigned*)&sbf[(long)(unsigned)rC * OUT_F + lo];
        unsigned uD = *(const unsigned*)&sbf[(long)(unsigned)rD * OUT_F + lo];
        float vA = __uint_as_float((unsigned)(rA >> 32));
        float vB = __uint_as_float((unsigned)(rB >> 32));
        float vC = __uint_as_float((unsigned)(rC >> 32));
        float vD = __uint_as_float((unsigned)(rD >> 32));
        aA.x += vA * bflo(uA); aA.y += vA * bfhi(uA);
        aB.x += vB * bflo(uB); aB.y += vB * bfhi(uB);
        aC.x += vC * bflo(uC); aC.y += vC * bfhi(uC);
        aD.x += vD * bflo(uD); aD.y += vD * bfhi(uD);
        ++i;
    }

    auto drain = [&](const ull* p, int j, int cnt, float2& acc) {
        for (; j + 2 <= cnt; j += 2) {
            ull r0_ = p[j], r1_ = p[j + 1];
            unsigned u0 = *(const unsigned*)&sbf[(long)(unsigned)r0_ * OUT_F + lo];
            unsigned u1 = *(const unsigned*)&sbf[(long)(unsigned)r1_ * OUT_F + lo];
            float v0 = __uint_as_float((unsigned)(r0_ >> 32));
            float v1 = __uint_as_float((unsigned)(r1_ >> 32));
            acc.x += v0 * bflo(u0) + v1 * bflo(u1);
            acc.y += v0 * bfhi(u0) + v1 * bfhi(u1);
        }
        if (j < cnt) {
            ull r0_ = p[j];
            unsigned u0 = *(const unsigned*)&sbf[(long)(unsigned)r0_ * OUT_F + lo];
            float v0 = __uint_as_float((unsigned)(r0_ >> 32));
            acc.x += v0 * bflo(u0);
            acc.y += v0 * bfhi(u0);
        }
    };
    drain(pA, i, cA, aA);
    drain(pB, i, cB, aB);
    drain(pC, i, cC, aC);
    drain(pD, i, cD, aD);

    __builtin_nontemporal_store(*(double*)&aA, (double*)&out[(long)r0 * OUT_F + lo]);
    __builtin_nontemporal_store(*(double*)&aB, (double*)&out[(long)(r0 + 1) * OUT_F + lo]);
    __builtin_nontemporal_store(*(double*)&aC, (double*)&out[(long)(r0 + 2) * OUT_F + lo]);
    __builtin_nontemporal_store(*(double*)&aD, (double*)&out[(long)(r0 + 3) * OUT_F + lo]);
}

extern "C" void kernel_launch(void* const* d_in, const int* in_sizes, int n_in,
                              void* d_out, int out_size, void* d_ws, size_t ws_size,
                              hipStream_t stream) {
    const float* x        = (const float*)d_in[0];
    const int*   edge_row = (const int*)d_in[1];
    const int*   edge_col = (const int*)d_in[2];
    const float* edge_val = (const float*)d_in[3];
    const float* weight   = (const float*)d_in[4];
    const float* bias     = (const float*)d_in[5];
    float* out = (float*)d_out;

    // workspace layout (bytes)
    char* wsb = (char*)d_ws;
    unsigned short* support_bf = (unsigned short*)wsb;           // 25,600,000 B
    ull* slots   = (ull*)(wsb + 25600000);                       // 100000*48*8 = 38,400,000 B
    int* rowcnt  = (int*)(wsb + 64000000);                       // 400,000 B
    unsigned short* wt = (unsigned short*)(wsb + 64400000);      // 65,536 B
    // total ~64.5 MB

    // 0) W -> transposed bf16
    wconv_kernel<<<dim3(128), 256, 0, stream>>>(weight, wt);

    // 1) zero per-row counters
    hipMemsetAsync(rowcnt, 0, N_NODES * sizeof(int), stream);

    // 2) fused: GEMM (support_bf = bf16(X@W)) || edge scatter into row slots
    fused_kernel<<<dim3(GEMM_BLOCKS + SCAT_BLOCKS), 256, 0, stream>>>(
        x, wt, support_bf, edge_row, edge_col, edge_val, rowcnt, slots);

    // 3) SpMM: 4 rows per wave
    spmm_kernel<<<dim3(N_NODES / 16), 256, 0, stream>>>(rowcnt, slots, support_bf,
                                                        bias, out);
}

// Round 9
// 135.370 us; speedup vs baseline: 1.5926x; 1.5926x over previous
//
#include <hip/hip_runtime.h>

#define N_NODES 100000
#define N_EDGES 1600000
#define IN_F 256
#define OUT_F 128

#define RPB 196                                   // rows per bucket
#define NBUSED ((N_NODES + RPB - 1) / RPB)        // 511 buckets
#define BCAP 3584          // records per bucket region (mean 3136, +8 sigma)
#define TILE 8192
#define NTILES ((N_EDGES + TILE - 1) / TILE)      // 196

typedef unsigned long long ull;
typedef __attribute__((ext_vector_type(4))) float f32x4;
typedef __attribute__((ext_vector_type(8))) short bf16x8;

__device__ __forceinline__ unsigned short f2bf(float f) {
    unsigned u = __float_as_uint(f);
    unsigned r = u + 0x7FFF + ((u >> 16) & 1);    // round-to-nearest-even
    return (unsigned short)(r >> 16);
}
__device__ __forceinline__ float bflo(unsigned u) { return __uint_as_float(u << 16); }
__device__ __forceinline__ float bfhi(unsigned u) { return __uint_as_float(u & 0xFFFF0000u); }

// ---------------------------------------------------------------------------
// wconv + cursor init: blocks 0..127 -> Wt[n][k] = bf16(W[k][n]);
// block 128 -> cursor[b] = b * BCAP (fixed bucket bases)
// ---------------------------------------------------------------------------
__global__ __launch_bounds__(256) void wconv_init_kernel(const float* __restrict__ W,
                                                         unsigned short* __restrict__ Wt,
                                                         int* __restrict__ cursor) {
    if (blockIdx.x == 128) {
        int t = threadIdx.x;
        cursor[t] = t * BCAP;
        cursor[t + 256] = (t + 256) * BCAP;
        return;
    }
    int idx = blockIdx.x * 256 + threadIdx.x;      // 32768 total
    int n = idx >> 8;
    int k = idx & 255;
    Wt[n * IN_F + k] = f2bf(W[k * OUT_F + n]);
}

// ---------------------------------------------------------------------------
// MFMA GEMM: support_bf[100000,128](bf16) = X[100000,256] @ W
// 128x128 tile, BK=32, 4 waves (2x2), 64x64 per wave. Reg-prefetch pipeline.
// ---------------------------------------------------------------------------
__global__ __launch_bounds__(256) void gemm_mfma_kernel(const float* __restrict__ X,
                                                        const unsigned short* __restrict__ Wt,
                                                        unsigned short* __restrict__ support_bf) {
    __shared__ __align__(16) unsigned short Albs[4][128][8];   // 8 KB
    __shared__ __align__(16) unsigned short Blbs[4][128][8];   // 8 KB

    const int tid = threadIdx.x;
    const int block_row = blockIdx.x * 128;

    const int srow = tid >> 1;          // 0..127
    const int shalf = tid & 1;

    const int wid = tid >> 6;
    const int lane = tid & 63;
    const int wr = wid >> 1, wc = wid & 1;
    const int fr = lane & 15;
    const int kb = lane >> 4;

    const int agrow = block_row + srow;
    const bool arow_ok = (agrow < N_NODES);
    const float* xrow = X + (long)agrow * IN_F;
    const unsigned short* wrow = Wt + srow * IN_F;

    f32x4 acc[4][4];
#pragma unroll
    for (int m = 0; m < 4; ++m)
#pragma unroll
        for (int n = 0; n < 4; ++n) acc[m][n] = (f32x4)0.f;

    // prologue loads (k0 = 0)
    float4 c0, c1, c2, c3;
    bf16x8 cb0, cb1;
    if (arow_ok) {
        c0 = *(const float4*)&xrow[shalf * 16 + 0];
        c1 = *(const float4*)&xrow[shalf * 16 + 4];
        c2 = *(const float4*)&xrow[shalf * 16 + 8];
        c3 = *(const float4*)&xrow[shalf * 16 + 12];
    } else {
        c0 = c1 = c2 = c3 = make_float4(0.f, 0.f, 0.f, 0.f);
    }
    cb0 = *(const bf16x8*)&wrow[shalf * 16];
    cb1 = *(const bf16x8*)&wrow[shalf * 16 + 8];

#pragma unroll
    for (int k0 = 0; k0 < IN_F; k0 += 32) {
        // stage current into LDS
        {
            bf16x8 p0, p1;
            p0[0] = (short)f2bf(c0.x); p0[1] = (short)f2bf(c0.y);
            p0[2] = (short)f2bf(c0.z); p0[3] = (short)f2bf(c0.w);
            p0[4] = (short)f2bf(c1.x); p0[5] = (short)f2bf(c1.y);
            p0[6] = (short)f2bf(c1.z); p0[7] = (short)f2bf(c1.w);
            p1[0] = (short)f2bf(c2.x); p1[1] = (short)f2bf(c2.y);
            p1[2] = (short)f2bf(c2.z); p1[3] = (short)f2bf(c2.w);
            p1[4] = (short)f2bf(c3.x); p1[5] = (short)f2bf(c3.y);
            p1[6] = (short)f2bf(c3.z); p1[7] = (short)f2bf(c3.w);
            *(bf16x8*)&Albs[shalf * 2][srow][0]     = p0;
            *(bf16x8*)&Albs[shalf * 2 + 1][srow][0] = p1;
            *(bf16x8*)&Blbs[shalf * 2][srow][0]     = cb0;
            *(bf16x8*)&Blbs[shalf * 2 + 1][srow][0] = cb1;
        }
        // prefetch next k-step (overlaps barrier + MFMA)
        float4 n0, n1, n2, n3;
        bf16x8 nb0, nb1;
        if (k0 + 32 < IN_F) {
            int kn = k0 + 32;
            if (arow_ok) {
                n0 = *(const float4*)&xrow[kn + shalf * 16 + 0];
                n1 = *(const float4*)&xrow[kn + shalf * 16 + 4];
                n2 = *(const float4*)&xrow[kn + shalf * 16 + 8];
                n3 = *(const float4*)&xrow[kn + shalf * 16 + 12];
            } else {
                n0 = n1 = n2 = n3 = make_float4(0.f, 0.f, 0.f, 0.f);
            }
            nb0 = *(const bf16x8*)&wrow[kn + shalf * 16];
            nb1 = *(const bf16x8*)&wrow[kn + shalf * 16 + 8];
        }
        __syncthreads();

        bf16x8 af[4], bfr[4];
#pragma unroll
        for (int m = 0; m < 4; ++m)
            af[m] = *(const bf16x8*)&Albs[kb][wr * 64 + m * 16 + fr][0];
#pragma unroll
        for (int n = 0; n < 4; ++n)
            bfr[n] = *(const bf16x8*)&Blbs[kb][wc * 64 + n * 16 + fr][0];
#pragma unroll
        for (int m = 0; m < 4; ++m)
#pragma unroll
            for (int n = 0; n < 4; ++n)
                acc[m][n] = __builtin_amdgcn_mfma_f32_16x16x32_bf16(af[m], bfr[n],
                                                                    acc[m][n], 0, 0, 0);
        __syncthreads();

        c0 = n0; c1 = n1; c2 = n2; c3 = n3;
        cb0 = nb0; cb1 = nb1;
    }

    // epilogue: C/D layout col=lane&15, row=(lane>>4)*4+reg ; write bf16
    const int crow0 = (lane >> 4) * 4;
    const int ccol = lane & 15;
#pragma unroll
    for (int m = 0; m < 4; ++m) {
#pragma unroll
        for (int reg = 0; reg < 4; ++reg) {
            int grow = block_row + wr * 64 + m * 16 + crow0 + reg;
            if (grow < N_NODES) {
#pragma unroll
                for (int n = 0; n < 4; ++n) {
                    int gcol = wc * 64 + n * 16 + ccol;
                    support_bf[(long)grow * OUT_F + gcol] = f2bf(acc[m][n][reg]);
                }
            }
        }
    }
}

// ---------------------------------------------------------------------------
// Shuffle: edges -> fixed-capacity bucket regions (bucket = row/RPB).
// Per-block LDS histogram -> one atomicAdd per non-empty bucket -> scatter.
// record = [val:f32 (63:32) | localrow:8 (31:24) | col:24 (23:0)]
// ---------------------------------------------------------------------------
__global__ __launch_bounds__(1024) void shuffle_kernel(const int* __restrict__ erow,
                                                       const int* __restrict__ ecol,
                                                       const float* __restrict__ eval,
                                                       int* __restrict__ cursor,
                                                       ull* __restrict__ bucketed) {
    __shared__ int lhist[NBUSED];
    __shared__ int lbase[NBUSED];
    const int e0 = blockIdx.x * TILE;
    const int e1 = min(e0 + TILE, N_EDGES);

    for (int i = threadIdx.x; i < NBUSED; i += 1024) lhist[i] = 0;
    __syncthreads();
    for (int e = e0 + threadIdx.x; e < e1; e += 1024)
        atomicAdd(&lhist[erow[e] / RPB], 1);
    __syncthreads();
    for (int i = threadIdx.x; i < NBUSED; i += 1024) {
        int c = lhist[i];
        lbase[i] = c ? atomicAdd(&cursor[i], c) : 0;
        lhist[i] = 0;                      // reuse as local cursor
    }
    __syncthreads();
    for (int e = e0 + threadIdx.x; e < e1; e += 1024) {
        int row = erow[e];                 // L2-hot re-read
        int b = row / RPB;
        int lr = row - b * RPB;
        int pos = lbase[b] + atomicAdd(&lhist[b], 1);
        if (pos < (b + 1) * BCAP) {        // fixed-region overflow guard
            ull rec = ((ull)__float_as_uint(eval[e]) << 32) |
                      ((unsigned)lr << 24) | (unsigned)ecol[e];
            bucketed[pos] = rec;
        }
    }
}

// ---------------------------------------------------------------------------
// bsort: per-bucket counting sort by local row -> sorted (fixed base) +
// per-row [start,end) pointers.
// ---------------------------------------------------------------------------
__global__ __launch_bounds__(256) void bsort_kernel(const int* __restrict__ cursor,
                                                    const ull* __restrict__ bucketed,
                                                    ull* __restrict__ sorted,
                                                    int* __restrict__ ostart,
                                                    int* __restrict__ oend) {
    const int b = blockIdx.x;
    const int r0 = b * RPB;
    const int nrows = min(RPB, N_NODES - r0);
    const int start = b * BCAP;
    const int cnt = min(cursor[b] - start, BCAP);

    __shared__ int lhist[RPB];
    __shared__ int lcur[RPB];
    __shared__ int lscan[256];
    const int tid = threadIdx.x;

    if (tid < RPB) lhist[tid] = 0;
    __syncthreads();
    for (int i = start + tid; i < start + cnt; i += 256) {
        int lr = (int)((bucketed[i] >> 24) & 0xFF);
        atomicAdd(&lhist[lr], 1);
    }
    __syncthreads();
    int v = (tid < RPB) ? lhist[tid] : 0;
    lscan[tid] = v;
    __syncthreads();
#pragma unroll
    for (int off = 1; off < 256; off <<= 1) {
        int t = (tid >= off) ? lscan[tid - off] : 0;
        __syncthreads();
        lscan[tid] += t;
        __syncthreads();
    }
    int excl = lscan[tid] - v;
    if (tid < nrows) {
        ostart[r0 + tid] = start + excl;
        oend[r0 + tid]   = start + excl + v;
        lcur[tid] = excl;
    }
    __syncthreads();
    for (int i = start + tid; i < start + cnt; i += 256) {
        ull rec = bucketed[i];             // L2-hot second read
        int lr = (int)((rec >> 24) & 0xFF);
        int p = atomicAdd(&lcur[lr], 1);
        sorted[start + p] = rec;
    }
}

// ---------------------------------------------------------------------------
// SpMM: FOUR rows per wave, depth-2 fused loop -> 8 gathers in flight.
// int4 start/end loads; plain loads on sorted; NT stores on out.
// ---------------------------------------------------------------------------
__global__ __launch_bounds__(256) void spmm_kernel(const int* __restrict__ ostart,
                                                   const int* __restrict__ oend,
                                                   const ull* __restrict__ sorted,
                                                   const unsigned short* __restrict__ sbf,
                                                   const float* __restrict__ b,
                                                   float* __restrict__ out) {
    const int wave = blockIdx.x * 4 + (threadIdx.x >> 6);
    const int lane = threadIdx.x & 63;
    const int r0 = wave * 4;                   // grid sized exactly: r0+3 < N_NODES
    const int lo = lane * 2;
    const float2 bb = *(const float2*)&b[lo];

    const int4 s4 = *(const int4*)&ostart[r0];
    const int4 e4 = *(const int4*)&oend[r0];
    const int cA = e4.x - s4.x, cB = e4.y - s4.y;
    const int cC = e4.z - s4.z, cD = e4.w - s4.w;
    const ull* pA = sorted + s4.x;
    const ull* pB = sorted + s4.y;
    const ull* pC = sorted + s4.z;
    const ull* pD = sorted + s4.w;

    float2 aA = bb, aB = bb, aC = bb, aD = bb;

    const int mn = min(min(cA, cB), min(cC, cD));
    int i = 0;
    // fused main loop: 2 edges from each of 4 rows -> 8 independent gathers
    for (; i + 2 <= mn; i += 2) {
        ull rA0 = pA[i], rA1 = pA[i + 1];
        ull rB0 = pB[i], rB1 = pB[i + 1];
        ull rC0 = pC[i], rC1 = pC[i + 1];
        ull rD0 = pD[i], rD1 = pD[i + 1];
        unsigned uA0 = *(const unsigned*)&sbf[(long)(rA0 & 0xFFFFFF) * OUT_F + lo];
        unsigned uA1 = *(const unsigned*)&sbf[(long)(rA1 & 0xFFFFFF) * OUT_F + lo];
        unsigned uB0 = *(const unsigned*)&sbf[(long)(rB0 & 0xFFFFFF) * OUT_F + lo];
        unsigned uB1 = *(const unsigned*)&sbf[(long)(rB1 & 0xFFFFFF) * OUT_F + lo];
        unsigned uC0 = *(const unsigned*)&sbf[(long)(rC0 & 0xFFFFFF) * OUT_F + lo];
        unsigned uC1 = *(const unsigned*)&sbf[(long)(rC1 & 0xFFFFFF) * OUT_F + lo];
        unsigned uD0 = *(const unsigned*)&sbf[(long)(rD0 & 0xFFFFFF) * OUT_F + lo];
        unsigned uD1 = *(const unsigned*)&sbf[(long)(rD1 & 0xFFFFFF) * OUT_F + lo];
        float vA0 = __uint_as_float((unsigned)(rA0 >> 32));
        float vA1 = __uint_as_float((unsigned)(rA1 >> 32));
        float vB0 = __uint_as_float((unsigned)(rB0 >> 32));
        float vB1 = __uint_as_float((unsigned)(rB1 >> 32));
        float vC0 = __uint_as_float((unsigned)(rC0 >> 32));
        float vC1 = __uint_as_float((unsigned)(rC1 >> 32));
        float vD0 = __uint_as_float((unsigned)(rD0 >> 32));
        float vD1 = __uint_as_float((unsigned)(rD1 >> 32));
        aA.x += vA0 * bflo(uA0) + vA1 * bflo(uA1);
        aA.y += vA0 * bfhi(uA0) + vA1 * bfhi(uA1);
        aB.x += vB0 * bflo(uB0) + vB1 * bflo(uB1);
        aB.y += vB0 * bfhi(uB0) + vB1 * bfhi(uB1);
        aC.x += vC0 * bflo(uC0) + vC1 * bflo(uC1);
        aC.y += vC0 * bfhi(uC0) + vC1 * bfhi(uC1);
        aD.x += vD0 * bflo(uD0) + vD1 * bflo(uD1);
        aD.y += vD0 * bfhi(uD0) + vD1 * bfhi(uD1);
    }
    if (i < mn) {                              // one more from each row
        ull rA = pA[i], rB = pB[i], rC = pC[i], rD = pD[i];
        unsigned uA = *(const unsigned*)&sbf[(long)(rA & 0xFFFFFF) * OUT_F + lo];
        unsigned uB = *(const unsigned*)&sbf[(long)(rB & 0xFFFFFF) * OUT_F + lo];
        unsigned uC = *(const unsigned*)&sbf[(long)(rC & 0xFFFFFF) * OUT_F + lo];
        unsigned uD = *(const unsigned*)&sbf[(long)(rD & 0xFFFFFF) * OUT_F + lo];
        float vA = __uint_as_float((unsigned)(rA >> 32));
        float vB = __uint_as_float((unsigned)(rB >> 32));
        float vC = __uint_as_float((unsigned)(rC >> 32));
        float vD = __uint_as_float((unsigned)(rD >> 32));
        aA.x += vA * bflo(uA); aA.y += vA * bfhi(uA);
        aB.x += vB * bflo(uB); aB.y += vB * bfhi(uB);
        aC.x += vC * bflo(uC); aC.y += vC * bfhi(uC);
        aD.x += vD * bflo(uD); aD.y += vD * bfhi(uD);
        ++i;
    }

    auto drain = [&](const ull* p, int j, int cnt, float2& acc) {
        for (; j + 2 <= cnt; j += 2) {
            ull r0_ = p[j], r1_ = p[j + 1];
            unsigned u0 = *(const unsigned*)&sbf[(long)(r0_ & 0xFFFFFF) * OUT_F + lo];
            unsigned u1 = *(const unsigned*)&sbf[(long)(r1_ & 0xFFFFFF) * OUT_F + lo];
            float v0 = __uint_as_float((unsigned)(r0_ >> 32));
            float v1 = __uint_as_float((unsigned)(r1_ >> 32));
            acc.x += v0 * bflo(u0) + v1 * bflo(u1);
            acc.y += v0 * bfhi(u0) + v1 * bfhi(u1);
        }
        if (j < cnt) {
            ull r0_ = p[j];
            unsigned u0 = *(const unsigned*)&sbf[(long)(r0_ & 0xFFFFFF) * OUT_F + lo];
            float v0 = __uint_as_float((unsigned)(r0_ >> 32));
            acc.x += v0 * bflo(u0);
            acc.y += v0 * bfhi(u0);
        }
    };
    drain(pA, i, cA, aA);
    drain(pB, i, cB, aB);
    drain(pC, i, cC, aC);
    drain(pD, i, cD, aD);

    __builtin_nontemporal_store(*(double*)&aA, (double*)&out[(long)r0 * OUT_F + lo]);
    __builtin_nontemporal_store(*(double*)&aB, (double*)&out[(long)(r0 + 1) * OUT_F + lo]);
    __builtin_nontemporal_store(*(double*)&aC, (double*)&out[(long)(r0 + 2) * OUT_F + lo]);
    __builtin_nontemporal_store(*(double*)&aD, (double*)&out[(long)(r0 + 3) * OUT_F + lo]);
}

extern "C" void kernel_launch(void* const* d_in, const int* in_sizes, int n_in,
                              void* d_out, int out_size, void* d_ws, size_t ws_size,
                              hipStream_t stream) {
    const float* x        = (const float*)d_in[0];
    const int*   edge_row = (const int*)d_in[1];
    const int*   edge_col = (const int*)d_in[2];
    const float* edge_val = (const float*)d_in[3];
    const float* weight   = (const float*)d_in[4];
    const float* bias     = (const float*)d_in[5];
    float* out = (float*)d_out;

    // workspace layout (byte offsets, all 16B aligned)
    char* wsb = (char*)d_ws;
    unsigned short* support_bf = (unsigned short*)wsb;            // 25,600,000 B
    ull* bucketed = (ull*)(wsb + 25600000);                       // 511*3584*8 = 14,651,392 B
    ull* sorted   = (ull*)(wsb + 40251392);                       // 14,651,392 B
    int* ostart   = (int*)(wsb + 54902784);                       // 400,000 B
    int* oend     = (int*)(wsb + 55302784);                       // 400,000 B
    int* cursor   = (int*)(wsb + 55702784);                       // 2,048 B
    unsigned short* wt = (unsigned short*)(wsb + 55704832);       // 65,536 B
    // total ~55.8 MB

    // 0) W -> transposed bf16 ; cursor[b] = b*BCAP
    wconv_init_kernel<<<dim3(129), 256, 0, stream>>>(weight, wt, cursor);

    // 1) support_bf = bf16(X @ W)
    gemm_mfma_kernel<<<dim3((N_NODES + 127) / 128), 256, 0, stream>>>(x, wt, support_bf);

    // 2) shuffle edges into fixed bucket regions
    shuffle_kernel<<<dim3(NTILES), 1024, 0, stream>>>(edge_row, edge_col, edge_val,
                                                      cursor, bucketed);

    // 3) per-bucket counting sort -> sorted + per-row [start,end)
    bsort_kernel<<<dim3(NBUSED), 256, 0, stream>>>(cursor, bucketed, sorted, ostart, oend);

    // 4) SpMM: 4 rows per wave
    spmm_kernel<<<dim3(N_NODES / 16), 256, 0, stream>>>(ostart, oend, sorted, support_bf,
                                                        bias, out);
}